// Round 5
// baseline (609.781 us; speedup 1.0000x reference)
//
#include <hip/hip_runtime.h>

// LSTM B=2048, T=1024, H=50. Round 5: Round-4 design + OOB fix.
//
// BW=4 batches/block, grid=512 (2 blocks per CU, desynchronized stall overlap).
// Block = 256 thr = 4 waves. Per step:
//   MFMA : D = W' @ h^T, 13 tiles of 16 permuted gate rows (n'=4j+g) split
//          over 4 waves (wave w: tiles w, w+4, w+8 [, 12]). A = W' f16 hi+lo
//          in VGPRs (loaded once). B = h^T f16 from LDS (rows = batch, JPAD=88
//          f16 stride -> 2-way banks = free). Lane (b=L15<4, kq) of tile t
//          holds {i,f,g,o} of (unit j=4t+kq, batch b) in acc[0..3] -> one
//          f32x4 write to pairbuf[j*4+b].
//   barrier1
//   Epilogue: thread p<200 owns pair (j=p>>2, b=p&3): activations, c-state in
//          reg, h -> hbuf[(t+1)&1][b][j] f16. Dense: 40 trans instr/block.
//   barrier2
// FIX vs round 4: pairbuf sized PBUF=208 (tiles cover j=0..51; j=50,51 are
// zero-pad units whose writes previously went 128 B past the 200-entry buffer,
// corrupting hbuf batch-row 0 in a cross-wave race -> absmax 7.3e-3).

#define H     50
#define TT    1024
#define BATCH 2048
#define BW    4
#define JPAD  88      // f16 per hbuf row: 176 B = 44 words -> 2-way banks
#define NPAIR 200     // real pairs = H * BW
#define PBUF  208     // buffer slots incl. pad units j=50,51 (52*4)

typedef float    f32x4 __attribute__((ext_vector_type(4)));
typedef _Float16 f16x8 __attribute__((ext_vector_type(8)));

__device__ __forceinline__ float fast_sigmoid(float x) {
    float e = __builtin_amdgcn_exp2f(-1.4426950408889634f * x);
    return __builtin_amdgcn_rcpf(1.0f + e);
}
__device__ __forceinline__ float fast_tanh(float x) {
    float e = __builtin_amdgcn_exp2f(2.8853900817779268f * x);
    return 1.0f - 2.0f * __builtin_amdgcn_rcpf(e + 1.0f);
}

__global__ __launch_bounds__(256, 2) void lstm_kernel(
    const float* __restrict__ x,      // [B, T]
    const float* __restrict__ W_ih,   // [200]
    const float* __restrict__ W_hh,   // [200, 50]
    const float* __restrict__ b_ih,   // [200]
    const float* __restrict__ b_hh,   // [200]
    const float* __restrict__ W_lin,  // [50]
    const float* __restrict__ b_lin,  // [1]
    float* __restrict__ out)          // [B]
{
    __shared__ _Float16 hbuf[2][16][JPAD];   // h^T: [buf][batch-col][unit]
    __shared__ f32x4 pairbuf[PBUF];          // {i,f,g,o} per pair p = j*4+b

    const int tid  = threadIdx.x;
    const int wave = tid >> 6;
    const int lane = tid & 63;
    const int L15  = lane & 15;
    const int kq   = lane >> 4;
    const int b0   = blockIdx.x * BW;

    const int ntiles = (wave == 0) ? 4 : 3;   // wave w: tiles w+4i

    // ---- A fragments: permuted W' rows, f16 hi+lo, resident in VGPRs ----
    // A[m = L15][k = kf*32 + kq*8 + e] of tile t -> global row 16t+L15 = 4j+g
    f16x8 Ahi[4][2], Alo[4][2];
    #pragma unroll
    for (int i = 0; i < 4; ++i) {
        if (i >= ntiles) break;
        const int t  = wave + 4 * i;
        const int m  = t * 16 + L15;
        const int jm = m >> 2, gm = m & 3;
        #pragma unroll
        for (int kf = 0; kf < 2; ++kf) {
            f16x8 vh, vl;
            #pragma unroll
            for (int e = 0; e < 8; ++e) {
                int k = kf * 32 + kq * 8 + e;
                float w = (jm < H && k < H) ? W_hh[(gm * H + jm) * H + k] : 0.f;
                _Float16 h16 = (_Float16)w;
                vh[e] = h16;
                vl[e] = (_Float16)(w - (float)h16);
            }
            Ahi[i][kf] = vh; Alo[i][kf] = vl;
        }
    }

    // ---- epilogue constants: pair p = j*4 + b ----
    const int  p    = tid;
    const bool pact = (p < NPAIR);
    const int  pj   = p >> 2;
    const int  pb   = p & 3;
    float wih[4], bias[4];
    #pragma unroll
    for (int g = 0; g < 4; ++g) {
        wih[g]  = pact ? W_ih[g * H + pj] : 0.f;
        bias[g] = pact ? (b_ih[g * H + pj] + b_hh[g * H + pj]) : 0.f;
    }
    const float wlin = pact ? W_lin[pj] : 0.f;

    // x prefetch for this pair's batch (same-address lanes -> L1 broadcast)
    const float* xrow = x + (size_t)(b0 + (pact ? pb : 0)) * TT;
    float4 xcur = *(const float4*)(xrow);
    float4 xnxt = *(const float4*)(xrow + 4);

    // ---- zero h buffers (h0 = 0; pad cols/units stay 0 forever) ----
    for (int i = tid; i < 2 * 16 * JPAD; i += 256)
        ((_Float16*)hbuf)[i] = (_Float16)0.f;

    float c = 0.f, hlast = 0.f;
    __syncthreads();

    for (int t = 0; t < TT; ++t) {
        // ---- MFMA phase ----
        const _Float16* hb = &hbuf[t & 1][L15][0];
        f16x8 B0 = *(const f16x8*)(hb + kq * 8);        // k = 0..31
        f16x8 B1 = *(const f16x8*)(hb + 32 + kq * 8);   // k = 32..63
        #pragma unroll
        for (int i = 0; i < 4; ++i) {
            if (i >= ntiles) break;
            f32x4 acc = {0.f, 0.f, 0.f, 0.f};
            acc = __builtin_amdgcn_mfma_f32_16x16x32_f16(Ahi[i][0], B0, acc, 0, 0, 0);
            acc = __builtin_amdgcn_mfma_f32_16x16x32_f16(Ahi[i][1], B1, acc, 0, 0, 0);
            acc = __builtin_amdgcn_mfma_f32_16x16x32_f16(Alo[i][0], B0, acc, 0, 0, 0);
            acc = __builtin_amdgcn_mfma_f32_16x16x32_f16(Alo[i][1], B1, acc, 0, 0, 0);
            if (L15 < BW) {
                const int tt = wave + 4 * i;
                pairbuf[(4 * tt + kq) * BW + L15] = acc;   // j=4tt+kq<=51, in-bounds in PBUF
            }
        }
        __syncthreads();   // gates visible

        // ---- dense per-pair epilogue ----
        if (pact) {
            f32x4 g4 = pairbuf[p];
            const float xv = ((const float*)&xcur)[t & 3];
            if ((t & 3) == 3) {
                xcur = xnxt;
                int off = t + 5; if (off > TT - 4) off = TT - 4;
                xnxt = *(const float4*)(xrow + off);
            }
            float i_ = fast_sigmoid(g4[0] + __builtin_fmaf(wih[0], xv, bias[0]));
            float f_ = fast_sigmoid(g4[1] + __builtin_fmaf(wih[1], xv, bias[1]));
            float g_ = fast_tanh   (g4[2] + __builtin_fmaf(wih[2], xv, bias[2]));
            float o_ = fast_sigmoid(g4[3] + __builtin_fmaf(wih[3], xv, bias[3]));
            c = __builtin_fmaf(f_, c, i_ * g_);
            float h = o_ * fast_tanh(c);
            hlast = h;
            hbuf[(t + 1) & 1][pb][pj] = (_Float16)h;
        }
        __syncthreads();   // new h visible
    }

    // ---- head: out[b] = sum_j W_lin[j] * h[j][b] + b_lin ----
    float* red = (float*)pairbuf;
    if (pact) red[p] = wlin * hlast;
    __syncthreads();
    if (tid < BW) {
        float s = b_lin[0];
        #pragma unroll 5
        for (int j = 0; j < H; ++j) s += red[j * BW + tid];
        out[b0 + tid] = s;
    }
}

extern "C" void kernel_launch(void* const* d_in, const int* in_sizes, int n_in,
                              void* d_out, int out_size, void* d_ws, size_t ws_size,
                              hipStream_t stream) {
    const float* x     = (const float*)d_in[0];
    const float* W_ih  = (const float*)d_in[1];
    const float* W_hh  = (const float*)d_in[2];
    const float* b_ih  = (const float*)d_in[3];
    const float* b_hh  = (const float*)d_in[4];
    const float* W_lin = (const float*)d_in[5];
    const float* b_lin = (const float*)d_in[6];
    float* out = (float*)d_out;

    dim3 grid(BATCH / BW);    // 512 blocks -> 2 per CU
    dim3 block(256);          // 4 waves
    lstm_kernel<<<grid, block, 0, stream>>>(x, W_ih, W_hh, b_ih, b_hh,
                                            W_lin, b_lin, out);
}